// Round 17
// baseline (3846.395 us; speedup 1.0000x reference)
//
#include <hip/hip_runtime.h>
#include <math.h>

#define NN 2048
#define BB 32
#define LL 12
#define HHH 12
#define UU 64
#define STR 68                 // slab row width: [h 64 | x 2 | pad 2]
#define SLAB (BB*STR)          // 2176 floats per node
#define SEGS 8
#define SEGW (SLAB/SEGS)       // 272: one column-segment per XCD
#define MR (NN*BB)             // 65536
#define CSR_CAP 262144
#define PACK_HALF 28672        // 7ks*4nf*2prec*64lane*8j halfwords per 64-col half

typedef short bfrag __attribute__((ext_vector_type(8)));
typedef float ffrag __attribute__((ext_vector_type(4)));

__device__ __forceinline__ float sigm(float x) { return 1.0f / (1.0f + __expf(-x)); }
__device__ __forceinline__ float tanhfast(float x) {
  float e = __expf(2.0f * x);
  return 1.0f - 2.0f / (e + 1.0f);
}

// fp32 -> (bf16 hi, bf16 lo) split, round-to-nearest-even both halves
__device__ __forceinline__ void cvt8(const float* a, bfrag* hi, bfrag* lo) {
  bfrag H, L;
  #pragma unroll
  for (int j = 0; j < 8; ++j) {
    unsigned u = __float_as_uint(a[j]);
    unsigned hb = (u + 0x7FFFu + ((u >> 16) & 1u)) >> 16;
    float rem = a[j] - __uint_as_float(hb << 16);
    unsigned u2 = __float_as_uint(rem);
    unsigned lb = (u2 + 0x7FFFu + ((u2 >> 16) & 1u)) >> 16;
    H[j] = (short)hb; L[j] = (short)lb;
  }
  *hi = H; *lo = L;
}

// ---------------- CSR build (deterministic) ----------------
__global__ __launch_bounds__(256) void k_row_count(const float* __restrict__ S, int* __restrict__ cnt) {
  int m = blockIdx.x;
  const float* row = S + (size_t)m * NN;
  int c = 0;
  for (int i = threadIdx.x; i < NN; i += 256) c += (row[i] != 0.0f);
  __shared__ int sm[4];
  for (int off = 32; off; off >>= 1) c += __shfl_down(c, off, 64);
  if ((threadIdx.x & 63) == 0) sm[threadIdx.x >> 6] = c;
  __syncthreads();
  if (threadIdx.x == 0) cnt[m] = sm[0] + sm[1] + sm[2] + sm[3];
}

__global__ __launch_bounds__(256) void k_scan(const int* __restrict__ cnt, int* __restrict__ rp) {
  __shared__ int tot[256];
  int t = threadIdx.x;
  int base = t * 8;
  int v[8]; int s = 0;
  #pragma unroll
  for (int k = 0; k < 8; ++k) { v[k] = cnt[base + k]; s += v[k]; }
  tot[t] = s;
  __syncthreads();
  for (int off = 1; off < 256; off <<= 1) {
    int add = (t >= off) ? tot[t - off] : 0;
    __syncthreads();
    tot[t] += add;
    __syncthreads();
  }
  int run = (t == 0) ? 0 : tot[t - 1];
  #pragma unroll
  for (int k = 0; k < 8; ++k) { rp[base + k] = run; run += v[k]; }
  if (t == 255) rp[NN] = run;
}

// cols stored PRE-SCALED: cols[k] = column_node * SLAB
__global__ __launch_bounds__(256) void k_fill(const float* __restrict__ S, const int* __restrict__ rp,
                                              int* __restrict__ cols, float* __restrict__ vals) {
  int m = blockIdx.x;
  const float* row = S + (size_t)m * NN;
  __shared__ int wsum[4];
  __shared__ int chunkbase;
  if (threadIdx.x == 0) chunkbase = rp[m];
  __syncthreads();
  int lane = threadIdx.x & 63, w = threadIdx.x >> 6;
  for (int ch = 0; ch < NN / 256; ++ch) {
    int i = ch * 256 + threadIdx.x;
    float val = row[i];
    bool p = (val != 0.0f);
    unsigned long long mask = __ballot(p);
    int rank = __popcll(mask & ((1ull << lane) - 1ull));
    if (lane == 0) wsum[w] = __popcll(mask);
    __syncthreads();
    int off = 0;
    for (int q = 0; q < w; ++q) off += wsum[q];
    if (p) { int k = chunkbase + off + rank; cols[k] = i * SLAB; vals[k] = val; }
    __syncthreads();
    if (threadIdx.x == 0) chunkbase += wsum[0] + wsum[1] + wsum[2] + wsum[3];
    __syncthreads();
  }
}

// ---------------- weight pack: fragment-linear bf16 hi/lo, X0-FOLDED ----------------
// kb0 -> W0 - W2 (cat), kb1 -> W1 (T1), kb2 -> 2*W2 (T2' = S*T1)
__global__ __launch_bounds__(256) void k_pack(const float* __restrict__ Wsrc, unsigned short* __restrict__ dst,
                                              int CIN_, int NO) {
  int idx = blockIdx.x * 256 + threadIdx.x;
  int nh_count = NO >> 6;
  int tot = nh_count * 7 * 4 * 64 * 8;
  if (idx >= tot) return;
  int j = idx & 7;
  int r1 = idx >> 3;  int lane = r1 & 63;
  int r2 = r1 >> 6;   int nf = r2 & 3;
  int r3 = r2 >> 2;   int ks = r3 % 7; int nh = r3 / 7;
  int grp = lane >> 4, l15 = lane & 15;
  int col = nh*64 + nf*16 + l15;
  float wv = 0.0f;
  int kb = -1, c = 0;
  if (ks < 6) {
    kb = ks >> 1;
    c = CIN_ + (ks & 1)*32 + grp*8 + j;
  } else {
    int q = grp*8 + j;
    if (q < 3*CIN_) { kb = q / CIN_; c = q % CIN_; }
  }
  if (kb >= 0) {
    float w0 = Wsrc[((size_t)c*3 + 0)*NO + col];
    float w1 = Wsrc[((size_t)c*3 + 1)*NO + col];
    float w2 = Wsrc[((size_t)c*3 + 2)*NO + col];
    wv = (kb == 0) ? (w0 - w2) : ((kb == 1) ? w1 : 2.0f*w2);
  }
  unsigned u = __float_as_uint(wv);
  unsigned hb = (u + 0x7FFFu + ((u >> 16) & 1u)) >> 16;
  float rem = wv - __uint_as_float(hb << 16);
  unsigned u2 = __float_as_uint(rem);
  unsigned lb = (u2 + 0x7FFFu + ((u2 >> 16) & 1u)) >> 16;
  size_t basehi = ((size_t)nh*PACK_HALF) + ((((size_t)ks*4 + nf)*2 + 0)*64 + lane)*8 + j;
  size_t baselo = ((size_t)nh*PACK_HALF) + ((((size_t)ks*4 + nf)*2 + 1)*64 + lane)*8 + j;
  dst[basehi] = (unsigned short)hb;
  dst[baselo] = (unsigned short)lb;
}

// ---------------- write enc x_t columns into the cat slab (t=0 bootstrap only) ----------------
__global__ __launch_bounds__(256) void k_setx(const float* __restrict__ hist, float* __restrict__ cat, int t) {
  int idx = blockIdx.x * 256 + threadIdx.x;      // 0 .. MR*2-1
  if (idx >= MR * 2) return;
  int c = idx & 1, row = idx >> 1;
  int n = row >> 5, b = row & 31;
  cat[(size_t)row * STR + 64 + c] = hist[(((size_t)(b * LL + t)) * NN + n) * 2 + c];
}

// ---------------- pure diffusion hop: Y = S . X  (seg-per-XCD, 4 nodes x 8-wide = 32 MLP) ----------------
__global__ __launch_bounds__(320) void k_hop(
    const int* __restrict__ rp, const int* __restrict__ colsS, const float* __restrict__ vals,
    const float* __restrict__ src, float* __restrict__ Y) {
  int orig = blockIdx.x;                         // 0..4095
  int seg = orig & 7;                            // XCD x owns seg x
  int quad = orig >> 3;                          // 0..511
  int n0 = quad * 4;
  int tid = threadIdx.x;
  if (tid >= SEGW) return;                       // no barriers: early-exit safe
  int w0 = seg * SEGW + tid;
  int ja  = __builtin_amdgcn_readfirstlane(rp[n0]);
  int ja1 = __builtin_amdgcn_readfirstlane(rp[n0 + 1]);
  int jb  = ja1;                                 // CSR rows contiguous
  int jb1 = __builtin_amdgcn_readfirstlane(rp[n0 + 2]);
  int jc  = jb1;
  int jc1 = __builtin_amdgcn_readfirstlane(rp[n0 + 3]);
  int jd  = jc1;
  int jd1 = __builtin_amdgcn_readfirstlane(rp[n0 + 4]);
  float aA0 = 0.f, aA1 = 0.f, aB0 = 0.f, aB1 = 0.f;
  float aC0 = 0.f, aC1 = 0.f, aD0 = 0.f, aD1 = 0.f;

  // main loop: 32 independent gathers in flight (4 nodes x 8-wide)
  while (ja + 8 <= ja1 && jb + 8 <= jb1 && jc + 8 <= jc1 && jd + 8 <= jd1) {
    int oa[8], ob[8], oc[8], od[8];
    float sa[8], sb[8], sc[8], sd[8];
    #pragma unroll
    for (int q = 0; q < 8; ++q) {
      oa[q] = colsS[ja + q]; sa[q] = vals[ja + q];
      ob[q] = colsS[jb + q]; sb[q] = vals[jb + q];
      oc[q] = colsS[jc + q]; sc[q] = vals[jc + q];
      od[q] = colsS[jd + q]; sd[q] = vals[jd + q];
    }
    float va[8], vb[8], vc[8], vd[8];
    #pragma unroll
    for (int q = 0; q < 8; ++q) {
      va[q] = src[oa[q] + w0]; vb[q] = src[ob[q] + w0];
      vc[q] = src[oc[q] + w0]; vd[q] = src[od[q] + w0];
    }
    #pragma unroll
    for (int q = 0; q < 8; ++q) {
      if (q & 1) {
        aA1 = fmaf(sa[q], va[q], aA1); aB1 = fmaf(sb[q], vb[q], aB1);
        aC1 = fmaf(sc[q], vc[q], aC1); aD1 = fmaf(sd[q], vd[q], aD1);
      } else {
        aA0 = fmaf(sa[q], va[q], aA0); aB0 = fmaf(sb[q], vb[q], aB0);
        aC0 = fmaf(sc[q], vc[q], aC0); aD0 = fmaf(sd[q], vd[q], aD0);
      }
    }
    ja += 8; jb += 8; jc += 8; jd += 8;
  }
  // per-node tails: 8-wide, 4-wide, scalar
  #define TAIL(jx, jx1, X0, X1)                                                    \
    for (; jx + 8 <= jx1; jx += 8) {                                               \
      int to[8]; float ts[8];                                                      \
      _Pragma("unroll")                                                            \
      for (int q = 0; q < 8; ++q) { to[q] = colsS[jx + q]; ts[q] = vals[jx + q]; } \
      float tv[8];                                                                 \
      _Pragma("unroll")                                                            \
      for (int q = 0; q < 8; ++q) tv[q] = src[to[q] + w0];                         \
      _Pragma("unroll")                                                            \
      for (int q = 0; q < 8; ++q) {                                                \
        if (q & 1) X1 = fmaf(ts[q], tv[q], X1);                                    \
        else       X0 = fmaf(ts[q], tv[q], X0);                                    \
      }                                                                            \
    }                                                                              \
    for (; jx + 4 <= jx1; jx += 4) {                                               \
      int   o0 = colsS[jx],  o1 = colsS[jx+1], o2 = colsS[jx+2], o3 = colsS[jx+3]; \
      float s0 = vals[jx],   s1 = vals[jx+1],  s2 = vals[jx+2],  s3 = vals[jx+3];  \
      float v0 = src[o0 + w0], v1 = src[o1 + w0];                                  \
      float v2 = src[o2 + w0], v3 = src[o3 + w0];                                  \
      X0 = fmaf(s0, v0, X0); X1 = fmaf(s1, v1, X1);                                \
      X0 = fmaf(s2, v2, X0); X1 = fmaf(s3, v3, X1);                                \
    }                                                                              \
    for (; jx < jx1; ++jx) X0 = fmaf(vals[jx], src[colsS[jx] + w0], X0);
  TAIL(ja, ja1, aA0, aA1)
  TAIL(jb, jb1, aB0, aB1)
  TAIL(jc, jc1, aC0, aC1)
  TAIL(jd, jd1, aD0, aD1)
  #undef TAIL

  Y[(size_t)(n0 + 0) * SLAB + w0] = aA0 + aA1;
  Y[(size_t)(n0 + 1) * SLAB + w0] = aB0 + aB1;
  Y[(size_t)(n0 + 2) * SLAB + w0] = aC0 + aC1;
  Y[(size_t)(n0 + 3) * SLAB + w0] = aD0 + aD1;
}

// ================= gate GEMM (LDS-staged B, XCD-paired halves, deep A-prefetch) =================
// 512 threads, 128 rows x 64 cols; grid = (MR/128)*2 = 1024 = 64 groups of 16.
// bid = q*16 + r: nfh = r>>3, pair = q*8 + (r&7)  ->  both halves of a row-span share an XCD.
template<int CATM>   // 1 enc (CIN=2), 2 dec (CIN=1)
__global__ __launch_bounds__(512, 4) void k_gate(
    const float* __restrict__ catP, const float* __restrict__ T1P, const float* __restrict__ T2P,
    const unsigned short* __restrict__ Bpack, const float* __restrict__ bg,
    float* __restrict__ zP, float* __restrict__ Ug) {
  __shared__ __align__(16) unsigned short Bl[PACK_HALF];
  int tid = threadIdx.x;
  int bid = blockIdx.x;
  int q = bid >> 4, r = bid & 15;
  int nfh = r >> 3;                       // 0: r-gate -> z ; 1: u-gate -> Ug
  int r0 = (q * 8 + (r & 7)) * 128;
  int w = tid >> 6, lane = tid & 63, grp = lane >> 4, l15 = lane & 15;
  int row0 = r0 + w*16 + l15;

  // ---- deep A-prefetch (issued before staging so they overlap) ----
  float av[7][8];
  #pragma unroll
  for (int ks = 0; ks < 6; ++ks) {
    const float* p0 = (ks < 2) ? catP : ((ks < 4) ? T1P : T2P);
    const float* a0 = p0 + (size_t)row0*STR + (ks & 1)*32 + grp*8;
    *(float4*)(av[ks])     = *(const float4*)a0;
    *(float4*)(av[ks] + 4) = *(const float4*)(a0 + 4);
  }
  #pragma unroll
  for (int j2 = 0; j2 < 8; ++j2) av[6][j2] = 0.f;
  if (grp == 0) {
    size_t rb = (size_t)row0*STR + 64;
    if (CATM == 1) {
      av[6][0] = catP[rb];  av[6][1] = catP[rb + 1];
      av[6][2] = T1P[rb];   av[6][3] = T1P[rb + 1];
      av[6][4] = T2P[rb];   av[6][5] = T2P[rb + 1];
    } else {
      av[6][0] = catP[rb];
      av[6][1] = T1P[rb];
      av[6][2] = T2P[rb];
    }
  }

  {
    const float4* srcv = (const float4*)(Bpack + (size_t)nfh * PACK_HALF);
    float4* dstv = (float4*)Bl;
    #pragma unroll
    for (int i = 0; i < PACK_HALF/8/512; ++i) dstv[tid + 512*i] = srcv[tid + 512*i];
  }
  __syncthreads();

  ffrag acc[4];
  #pragma unroll
  for (int nf = 0; nf < 4; ++nf) acc[nf] = (ffrag){0.f, 0.f, 0.f, 0.f};
  #pragma unroll
  for (int ks = 0; ks < 7; ++ks) {
    bfrag ah0, al0;
    cvt8(av[ks], &ah0, &al0);
    #pragma unroll
    for (int nf = 0; nf < 4; ++nf) {
      const unsigned short* bb = Bl + (((size_t)(ks*4 + nf)*2)*64 + lane)*8;
      bfrag bh = *(const bfrag*)bb;
      bfrag bl = *(const bfrag*)(bb + 512);
      acc[nf] = __builtin_amdgcn_mfma_f32_16x16x32_bf16(ah0, bh, acc[nf], 0, 0, 0);
      acc[nf] = __builtin_amdgcn_mfma_f32_16x16x32_bf16(ah0, bl, acc[nf], 0, 0, 0);
      acc[nf] = __builtin_amdgcn_mfma_f32_16x16x32_bf16(al0, bh, acc[nf], 0, 0, 0);
    }
  }
  // ---- epilogue ----
  float bgv[4];
  #pragma unroll
  for (int nf = 0; nf < 4; ++nf) bgv[nf] = bg[nfh*64 + nf*16 + l15];
  #pragma unroll
  for (int reg = 0; reg < 4; ++reg) {
    int row = r0 + w*16 + grp*4 + reg;
    #pragma unroll
    for (int nf = 0; nf < 4; ++nf) {
      int col = nf*16 + l15;
      float v = sigm(acc[nf][reg] + bgv[nf]);
      if (nfh == 0) {
        float ho = catP[(size_t)row*STR + col];
        zP[(size_t)row*STR + col] = v * ho;
      } else {
        Ug[(size_t)row*UU + col] = v;
      }
    }
  }
  if (nfh == 0 && l15 == 0) {
    #pragma unroll
    for (int reg = 0; reg < 4; ++reg) {
      int row = r0 + w*16 + grp*4 + reg;
      size_t zb = (size_t)row*STR;
      zP[zb + 64] = catP[zb + 64];
      zP[zb + 65] = (CATM == 1) ? catP[zb + 65] : 0.f;
      zP[zb + 66] = 0.f; zP[zb + 67] = 0.f;
    }
  }
}

// ================= cand GEMM (LDS-staged B, deep A-prefetch) =================
// 512 threads, 128 rows x 64 cols; grid = MR/128
template<bool DEC>
__global__ __launch_bounds__(512, 4) void k_cand(
    const float* __restrict__ zP, const float* __restrict__ T1P, const float* __restrict__ T2P,
    const unsigned short* __restrict__ Bpack, const float* __restrict__ bc,
    const float* __restrict__ Ug, const float* __restrict__ catCur,
    float* __restrict__ catNext,
    const float* __restrict__ Wp, const float* __restrict__ bp,
    float* __restrict__ out, const float* __restrict__ hist, int tpar) {
  __shared__ __align__(16) unsigned short Bl[PACK_HALF];
  int tid = threadIdx.x;
  int r0 = blockIdx.x * 128;
  int w = tid >> 6, lane = tid & 63, grp = lane >> 4, l15 = lane & 15;
  int row0 = r0 + w*16 + l15;

  float av[7][8];
  #pragma unroll
  for (int ks = 0; ks < 6; ++ks) {
    const float* p0 = (ks < 2) ? zP : ((ks < 4) ? T1P : T2P);
    const float* a0 = p0 + (size_t)row0*STR + (ks & 1)*32 + grp*8;
    *(float4*)(av[ks])     = *(const float4*)a0;
    *(float4*)(av[ks] + 4) = *(const float4*)(a0 + 4);
  }
  #pragma unroll
  for (int j2 = 0; j2 < 8; ++j2) av[6][j2] = 0.f;
  if (grp == 0) {
    size_t rb = (size_t)row0*STR + 64;
    if (!DEC) {
      av[6][0] = zP[rb];  av[6][1] = zP[rb + 1];
      av[6][2] = T1P[rb]; av[6][3] = T1P[rb + 1];
      av[6][4] = T2P[rb]; av[6][5] = T2P[rb + 1];
    } else {
      av[6][0] = zP[rb];
      av[6][1] = T1P[rb];
      av[6][2] = T2P[rb];
    }
  }

  {
    const float4* srcv = (const float4*)Bpack;
    float4* dstv = (float4*)Bl;
    #pragma unroll
    for (int i = 0; i < PACK_HALF/8/512; ++i) dstv[tid + 512*i] = srcv[tid + 512*i];
  }
  __syncthreads();

  ffrag acc[4];
  #pragma unroll
  for (int nf = 0; nf < 4; ++nf) acc[nf] = (ffrag){0.f, 0.f, 0.f, 0.f};
  #pragma unroll
  for (int ks = 0; ks < 7; ++ks) {
    bfrag ah0, al0;
    cvt8(av[ks], &ah0, &al0);
    #pragma unroll
    for (int nf = 0; nf < 4; ++nf) {
      const unsigned short* bb = Bl + (((size_t)(ks*4 + nf)*2)*64 + lane)*8;
      bfrag bh = *(const bfrag*)bb;
      bfrag bl = *(const bfrag*)(bb + 512);
      acc[nf] = __builtin_amdgcn_mfma_f32_16x16x32_bf16(ah0, bh, acc[nf], 0, 0, 0);
      acc[nf] = __builtin_amdgcn_mfma_f32_16x16x32_bf16(ah0, bl, acc[nf], 0, 0, 0);
      acc[nf] = __builtin_amdgcn_mfma_f32_16x16x32_bf16(al0, bh, acc[nf], 0, 0, 0);
    }
  }
  float bcv[4], wpv[4];
  #pragma unroll
  for (int nf = 0; nf < 4; ++nf) {
    bcv[nf] = bc[nf*16 + l15];
    wpv[nf] = DEC ? Wp[nf*16 + l15] : 0.f;
  }
  float bp0 = DEC ? bp[0] : 0.f;
  #pragma unroll
  for (int reg = 0; reg < 4; ++reg) {
    int row = r0 + w*16 + grp*4 + reg;
    float p = 0.f;
    #pragma unroll
    for (int nf = 0; nf < 4; ++nf) {
      int col = nf*16 + l15;
      float cf = tanhfast(acc[nf][reg] + bcv[nf]);
      float u  = Ug[(size_t)row*UU + col];
      float ho = catCur[(size_t)row*STR + col];
      float hv = u * ho + (1.0f - u) * cf;
      catNext[(size_t)row*STR + col] = hv;
      if (DEC) p = fmaf(hv, wpv[nf], p);
    }
    if (DEC) {
      p += __shfl_xor(p, 1, 64);
      p += __shfl_xor(p, 2, 64);
      p += __shfl_xor(p, 4, 64);
      p += __shfl_xor(p, 8, 64);
      if (l15 == 0) {
        float val = p + bp0;
        int n = row >> 5, b = row & 31;
        out[((size_t)b*HHH + tpar)*NN + n] = val;
        catNext[(size_t)row*STR + 64] = val;   // next decoder input
        catNext[(size_t)row*STR + 65] = 0.f;
      }
    } else {
      if (l15 == 0) {
        int n = row >> 5, b = row & 31;
        bool hv2 = tpar < LL;
        const float* hx = hist + (((size_t)(b*LL + tpar)) * NN + n) * 2;
        catNext[(size_t)row*STR + 64] = hv2 ? hx[0] : 0.f;
        catNext[(size_t)row*STR + 65] = hv2 ? hx[1] : 0.f;
      }
    }
  }
}

extern "C" void kernel_launch(void* const* d_in, const int* in_sizes, int n_in,
                              void* d_out, int out_size, void* d_ws, size_t ws_size,
                              hipStream_t stream) {
  (void)in_sizes; (void)n_in; (void)out_size; (void)ws_size;
  const float* hist = (const float*)d_in[0];
  const float* support = (const float*)d_in[1];
  const float* eWg = (const float*)d_in[2];
  const float* ebg = (const float*)d_in[3];
  const float* eWc = (const float*)d_in[4];
  const float* ebc = (const float*)d_in[5];
  const float* dWg = (const float*)d_in[6];
  const float* dbg = (const float*)d_in[7];
  const float* dWc = (const float*)d_in[8];
  const float* dbc = (const float*)d_in[9];
  const float* Wp  = (const float*)d_in[10];
  const float* bp  = (const float*)d_in[11];
  float* out = (float*)d_out;

  char* base = (char*)d_ws;
  size_t off = 0;
  auto carve = [&](size_t bytes) -> void* {
    void* p = base + off;
    off += (bytes + 255) & ~(size_t)255;
    return p;
  };
  int*   cnt   = (int*)carve(NN * 4);
  int*   rpB   = (int*)carve((NN + 1) * 4);
  int*   colsB = (int*)carve(CSR_CAP * 4);
  float* valsB = (float*)carve(CSR_CAP * 4);
  unsigned short* Pge = (unsigned short*)carve(2 * PACK_HALF * 2);
  unsigned short* Pgd = (unsigned short*)carve(2 * PACK_HALF * 2);
  unsigned short* Pce = (unsigned short*)carve((size_t)PACK_HALF * 2);
  unsigned short* Pcd = (unsigned short*)carve((size_t)PACK_HALF * 2);
  float* T1P  = (float*)carve((size_t)NN * SLAB * 4);
  float* T2P  = (float*)carve((size_t)NN * SLAB * 4);
  float* zP   = (float*)carve((size_t)NN * SLAB * 4);
  float* UgF  = (float*)carve((size_t)MR * UU * 4);
  float* catA = (float*)carve((size_t)NN * SLAB * 4);
  float* catB = (float*)carve((size_t)NN * SLAB * 4);

  hipMemsetAsync(catA, 0, (size_t)NN * SLAB * 4, stream);
  hipMemsetAsync(catB, 0, (size_t)NN * SLAB * 4, stream);

  k_row_count<<<NN, 256, 0, stream>>>(support, cnt);
  k_scan<<<1, 256, 0, stream>>>(cnt, rpB);
  k_fill<<<NN, 256, 0, stream>>>(support, rpB, colsB, valsB);
  k_pack<<<112, 256, 0, stream>>>(eWg, Pge, 2, 128);
  k_pack<<<56, 256, 0, stream>>>(eWc, Pce, 2, 64);
  k_pack<<<112, 256, 0, stream>>>(dWg, Pgd, 1, 128);
  k_pack<<<56, 256, 0, stream>>>(dWc, Pcd, 1, 64);
  k_setx<<<(MR*2 + 255)/256, 256, 0, stream>>>(hist, catA, 0);

  float* hc = catA; float* hn = catB;
  for (int t = 0; t < LL; ++t) {
    k_hop<<<NN*SEGS/4, 320, 0, stream>>>(rpB, colsB, valsB, hc, T1P);
    k_hop<<<NN*SEGS/4, 320, 0, stream>>>(rpB, colsB, valsB, T1P, T2P);
    k_gate<1><<<MR/128*2, 512, 0, stream>>>(hc, T1P, T2P, Pge, ebg, zP, UgF);
    k_hop<<<NN*SEGS/4, 320, 0, stream>>>(rpB, colsB, valsB, zP, T1P);
    k_hop<<<NN*SEGS/4, 320, 0, stream>>>(rpB, colsB, valsB, T1P, T2P);
    k_cand<false><<<MR/128, 512, 0, stream>>>(zP, T1P, T2P, Pce, ebc, UgF, hc, hn,
                                              Wp, bp, out, hist, t + 1);
    float* tmp = hc; hc = hn; hn = tmp;
  }
  for (int t = 0; t < HHH; ++t) {
    k_hop<<<NN*SEGS/4, 320, 0, stream>>>(rpB, colsB, valsB, hc, T1P);
    k_hop<<<NN*SEGS/4, 320, 0, stream>>>(rpB, colsB, valsB, T1P, T2P);
    k_gate<2><<<MR/128*2, 512, 0, stream>>>(hc, T1P, T2P, Pgd, dbg, zP, UgF);
    k_hop<<<NN*SEGS/4, 320, 0, stream>>>(rpB, colsB, valsB, zP, T1P);
    k_hop<<<NN*SEGS/4, 320, 0, stream>>>(rpB, colsB, valsB, T1P, T2P);
    k_cand<true><<<MR/128, 512, 0, stream>>>(zP, T1P, T2P, Pcd, dbc, UgF, hc, hn,
                                             Wp, bp, out, hist, t);
    float* tmp = hc; hc = hn; hn = tmp;
  }
}

// Round 18
// 3674.846 us; speedup vs baseline: 1.0467x; 1.0467x over previous
//
#include <hip/hip_runtime.h>
#include <math.h>

#define NN 2048
#define BB 32
#define LL 12
#define HHH 12
#define UU 64
#define STR 68                 // slab row width: [h 64 | x 2 | pad 2]
#define SLAB (BB*STR)          // 2176 floats per node
#define SEGS 8
#define SEGW (SLAB/SEGS)       // 272: one column-segment per XCD
#define MR (NN*BB)             // 65536
#define CSR_CAP 262144
#define PACK_HALF 28672        // 7ks*4nf*2prec*64lane*8j halfwords per 64-col half

typedef short bfrag __attribute__((ext_vector_type(8)));
typedef float ffrag __attribute__((ext_vector_type(4)));

__device__ __forceinline__ float sigm(float x) { return 1.0f / (1.0f + __expf(-x)); }
__device__ __forceinline__ float tanhfast(float x) {
  float e = __expf(2.0f * x);
  return 1.0f - 2.0f / (e + 1.0f);
}

// fp32 -> (bf16 hi, bf16 lo) split, round-to-nearest-even both halves
__device__ __forceinline__ void cvt8(const float* a, bfrag* hi, bfrag* lo) {
  bfrag H, L;
  #pragma unroll
  for (int j = 0; j < 8; ++j) {
    unsigned u = __float_as_uint(a[j]);
    unsigned hb = (u + 0x7FFFu + ((u >> 16) & 1u)) >> 16;
    float rem = a[j] - __uint_as_float(hb << 16);
    unsigned u2 = __float_as_uint(rem);
    unsigned lb = (u2 + 0x7FFFu + ((u2 >> 16) & 1u)) >> 16;
    H[j] = (short)hb; L[j] = (short)lb;
  }
  *hi = H; *lo = L;
}

// ---------------- CSR build (deterministic) ----------------
__global__ __launch_bounds__(256) void k_row_count(const float* __restrict__ S, int* __restrict__ cnt) {
  int m = blockIdx.x;
  const float* row = S + (size_t)m * NN;
  int c = 0;
  for (int i = threadIdx.x; i < NN; i += 256) c += (row[i] != 0.0f);
  __shared__ int sm[4];
  for (int off = 32; off; off >>= 1) c += __shfl_down(c, off, 64);
  if ((threadIdx.x & 63) == 0) sm[threadIdx.x >> 6] = c;
  __syncthreads();
  if (threadIdx.x == 0) cnt[m] = sm[0] + sm[1] + sm[2] + sm[3];
}

__global__ __launch_bounds__(256) void k_scan(const int* __restrict__ cnt, int* __restrict__ rp) {
  __shared__ int tot[256];
  int t = threadIdx.x;
  int base = t * 8;
  int v[8]; int s = 0;
  #pragma unroll
  for (int k = 0; k < 8; ++k) { v[k] = cnt[base + k]; s += v[k]; }
  tot[t] = s;
  __syncthreads();
  for (int off = 1; off < 256; off <<= 1) {
    int add = (t >= off) ? tot[t - off] : 0;
    __syncthreads();
    tot[t] += add;
    __syncthreads();
  }
  int run = (t == 0) ? 0 : tot[t - 1];
  #pragma unroll
  for (int k = 0; k < 8; ++k) { rp[base + k] = run; run += v[k]; }
  if (t == 255) rp[NN] = run;
}

// cols stored PRE-SCALED: cols[k] = column_node * SLAB
__global__ __launch_bounds__(256) void k_fill(const float* __restrict__ S, const int* __restrict__ rp,
                                              int* __restrict__ cols, float* __restrict__ vals) {
  int m = blockIdx.x;
  const float* row = S + (size_t)m * NN;
  __shared__ int wsum[4];
  __shared__ int chunkbase;
  if (threadIdx.x == 0) chunkbase = rp[m];
  __syncthreads();
  int lane = threadIdx.x & 63, w = threadIdx.x >> 6;
  for (int ch = 0; ch < NN / 256; ++ch) {
    int i = ch * 256 + threadIdx.x;
    float val = row[i];
    bool p = (val != 0.0f);
    unsigned long long mask = __ballot(p);
    int rank = __popcll(mask & ((1ull << lane) - 1ull));
    if (lane == 0) wsum[w] = __popcll(mask);
    __syncthreads();
    int off = 0;
    for (int q = 0; q < w; ++q) off += wsum[q];
    if (p) { int k = chunkbase + off + rank; cols[k] = i * SLAB; vals[k] = val; }
    __syncthreads();
    if (threadIdx.x == 0) chunkbase += wsum[0] + wsum[1] + wsum[2] + wsum[3];
    __syncthreads();
  }
}

// ---------------- weight pack: fragment-linear bf16 hi/lo, X0-FOLDED ----------------
// kb0 -> W0 - W2 (cat), kb1 -> W1 (T1), kb2 -> 2*W2 (T2' = S*T1)
__global__ __launch_bounds__(256) void k_pack(const float* __restrict__ Wsrc, unsigned short* __restrict__ dst,
                                              int CIN_, int NO) {
  int idx = blockIdx.x * 256 + threadIdx.x;
  int nh_count = NO >> 6;
  int tot = nh_count * 7 * 4 * 64 * 8;
  if (idx >= tot) return;
  int j = idx & 7;
  int r1 = idx >> 3;  int lane = r1 & 63;
  int r2 = r1 >> 6;   int nf = r2 & 3;
  int r3 = r2 >> 2;   int ks = r3 % 7; int nh = r3 / 7;
  int grp = lane >> 4, l15 = lane & 15;
  int col = nh*64 + nf*16 + l15;
  float wv = 0.0f;
  int kb = -1, c = 0;
  if (ks < 6) {
    kb = ks >> 1;
    c = CIN_ + (ks & 1)*32 + grp*8 + j;
  } else {
    int q = grp*8 + j;
    if (q < 3*CIN_) { kb = q / CIN_; c = q % CIN_; }
  }
  if (kb >= 0) {
    float w0 = Wsrc[((size_t)c*3 + 0)*NO + col];
    float w1 = Wsrc[((size_t)c*3 + 1)*NO + col];
    float w2 = Wsrc[((size_t)c*3 + 2)*NO + col];
    wv = (kb == 0) ? (w0 - w2) : ((kb == 1) ? w1 : 2.0f*w2);
  }
  unsigned u = __float_as_uint(wv);
  unsigned hb = (u + 0x7FFFu + ((u >> 16) & 1u)) >> 16;
  float rem = wv - __uint_as_float(hb << 16);
  unsigned u2 = __float_as_uint(rem);
  unsigned lb = (u2 + 0x7FFFu + ((u2 >> 16) & 1u)) >> 16;
  size_t basehi = ((size_t)nh*PACK_HALF) + ((((size_t)ks*4 + nf)*2 + 0)*64 + lane)*8 + j;
  size_t baselo = ((size_t)nh*PACK_HALF) + ((((size_t)ks*4 + nf)*2 + 1)*64 + lane)*8 + j;
  dst[basehi] = (unsigned short)hb;
  dst[baselo] = (unsigned short)lb;
}

// ---------------- write enc x_t columns into the cat slab (t=0 bootstrap only) ----------------
__global__ __launch_bounds__(256) void k_setx(const float* __restrict__ hist, float* __restrict__ cat, int t) {
  int idx = blockIdx.x * 256 + threadIdx.x;      // 0 .. MR*2-1
  if (idx >= MR * 2) return;
  int c = idx & 1, row = idx >> 1;
  int n = row >> 5, b = row & 31;
  cat[(size_t)row * STR + 64 + c] = hist[(((size_t)(b * LL + t)) * NN + n) * 2 + c];
}

// ---------------- pure diffusion hop: Y = S . X  (seg-per-XCD, 2 nodes x 8-wide = 16 MLP) ----------------
__global__ __launch_bounds__(320) void k_hop(
    const int* __restrict__ rp, const int* __restrict__ colsS, const float* __restrict__ vals,
    const float* __restrict__ src, float* __restrict__ Y) {
  int orig = blockIdx.x;                         // 0..8191
  int seg = orig & 7;                            // XCD x owns seg x
  int pair = orig >> 3;                          // 0..1023
  int nodeA = pair * 2, nodeB = nodeA + 1;
  int tid = threadIdx.x;
  if (tid >= SEGW) return;                       // no barriers: early-exit safe
  int w0 = seg * SEGW + tid;
  int ja  = __builtin_amdgcn_readfirstlane(rp[nodeA]);
  int ja1 = __builtin_amdgcn_readfirstlane(rp[nodeA + 1]);
  int jb  = ja1;                                 // CSR rows contiguous
  int jb1 = __builtin_amdgcn_readfirstlane(rp[nodeB + 1]);
  float accA0 = 0.f, accA1 = 0.f, accB0 = 0.f, accB1 = 0.f;

  // main loop: 16 independent gathers in flight
  while (ja + 8 <= ja1 && jb + 8 <= jb1) {
    int oa[8], ob[8]; float sa[8], sb[8];
    #pragma unroll
    for (int q = 0; q < 8; ++q) {
      oa[q] = colsS[ja + q]; sa[q] = vals[ja + q];
      ob[q] = colsS[jb + q]; sb[q] = vals[jb + q];
    }
    float va[8], vb[8];
    #pragma unroll
    for (int q = 0; q < 8; ++q) { va[q] = src[oa[q] + w0]; vb[q] = src[ob[q] + w0]; }
    #pragma unroll
    for (int q = 0; q < 8; ++q) {
      if (q & 1) { accA1 = fmaf(sa[q], va[q], accA1); accB1 = fmaf(sb[q], vb[q], accB1); }
      else       { accA0 = fmaf(sa[q], va[q], accA0); accB0 = fmaf(sb[q], vb[q], accB0); }
    }
    ja += 8; jb += 8;
  }
  // node-A tail: 4-wide then scalar
  for (; ja + 4 <= ja1; ja += 4) {
    int   o0 = colsS[ja],  o1 = colsS[ja+1], o2 = colsS[ja+2], o3 = colsS[ja+3];
    float s0 = vals[ja],   s1 = vals[ja+1],  s2 = vals[ja+2],  s3 = vals[ja+3];
    float v0 = src[o0 + w0], v1 = src[o1 + w0], v2 = src[o2 + w0], v3 = src[o3 + w0];
    accA0 = fmaf(s0, v0, accA0); accA1 = fmaf(s1, v1, accA1);
    accA0 = fmaf(s2, v2, accA0); accA1 = fmaf(s3, v3, accA1);
  }
  for (; ja < ja1; ++ja) accA0 = fmaf(vals[ja], src[colsS[ja] + w0], accA0);
  // node-B tail: 4-wide then scalar
  for (; jb + 4 <= jb1; jb += 4) {
    int   o0 = colsS[jb],  o1 = colsS[jb+1], o2 = colsS[jb+2], o3 = colsS[jb+3];
    float s0 = vals[jb],   s1 = vals[jb+1],  s2 = vals[jb+2],  s3 = vals[jb+3];
    float v0 = src[o0 + w0], v1 = src[o1 + w0], v2 = src[o2 + w0], v3 = src[o3 + w0];
    accB0 = fmaf(s0, v0, accB0); accB1 = fmaf(s1, v1, accB1);
    accB0 = fmaf(s2, v2, accB0); accB1 = fmaf(s3, v3, accB1);
  }
  for (; jb < jb1; ++jb) accB0 = fmaf(vals[jb], src[colsS[jb] + w0], accB0);

  Y[(size_t)nodeA * SLAB + w0] = accA0 + accA1;
  Y[(size_t)nodeB * SLAB + w0] = accB0 + accB1;
}

// ================= gate GEMM (LDS-staged B, XCD-paired halves, deep A-prefetch) =================
// 512 threads, 128 rows x 64 cols; grid = (MR/128)*2 = 1024 = 64 groups of 16.
// bid = q*16 + r: nfh = r>>3, pair = q*8 + (r&7)  ->  both halves of a row-span share an XCD.
template<int CATM>   // 1 enc (CIN=2), 2 dec (CIN=1)
__global__ __launch_bounds__(512, 4) void k_gate(
    const float* __restrict__ catP, const float* __restrict__ T1P, const float* __restrict__ T2P,
    const unsigned short* __restrict__ Bpack, const float* __restrict__ bg,
    float* __restrict__ zP, float* __restrict__ Ug) {
  __shared__ __align__(16) unsigned short Bl[PACK_HALF];
  int tid = threadIdx.x;
  int bid = blockIdx.x;
  int q = bid >> 4, r = bid & 15;
  int nfh = r >> 3;                       // 0: r-gate -> z ; 1: u-gate -> Ug
  int r0 = (q * 8 + (r & 7)) * 128;
  int w = tid >> 6, lane = tid & 63, grp = lane >> 4, l15 = lane & 15;
  int row0 = r0 + w*16 + l15;

  // ---- deep A-prefetch (issued before staging so they overlap) ----
  float av[7][8];
  #pragma unroll
  for (int ks = 0; ks < 6; ++ks) {
    const float* p0 = (ks < 2) ? catP : ((ks < 4) ? T1P : T2P);
    const float* a0 = p0 + (size_t)row0*STR + (ks & 1)*32 + grp*8;
    *(float4*)(av[ks])     = *(const float4*)a0;
    *(float4*)(av[ks] + 4) = *(const float4*)(a0 + 4);
  }
  #pragma unroll
  for (int j2 = 0; j2 < 8; ++j2) av[6][j2] = 0.f;
  if (grp == 0) {
    size_t rb = (size_t)row0*STR + 64;
    if (CATM == 1) {
      av[6][0] = catP[rb];  av[6][1] = catP[rb + 1];
      av[6][2] = T1P[rb];   av[6][3] = T1P[rb + 1];
      av[6][4] = T2P[rb];   av[6][5] = T2P[rb + 1];
    } else {
      av[6][0] = catP[rb];
      av[6][1] = T1P[rb];
      av[6][2] = T2P[rb];
    }
  }

  {
    const float4* srcv = (const float4*)(Bpack + (size_t)nfh * PACK_HALF);
    float4* dstv = (float4*)Bl;
    #pragma unroll
    for (int i = 0; i < PACK_HALF/8/512; ++i) dstv[tid + 512*i] = srcv[tid + 512*i];
  }
  __syncthreads();

  ffrag acc[4];
  #pragma unroll
  for (int nf = 0; nf < 4; ++nf) acc[nf] = (ffrag){0.f, 0.f, 0.f, 0.f};
  #pragma unroll
  for (int ks = 0; ks < 7; ++ks) {
    bfrag ah0, al0;
    cvt8(av[ks], &ah0, &al0);
    #pragma unroll
    for (int nf = 0; nf < 4; ++nf) {
      const unsigned short* bb = Bl + (((size_t)(ks*4 + nf)*2)*64 + lane)*8;
      bfrag bh = *(const bfrag*)bb;
      bfrag bl = *(const bfrag*)(bb + 512);
      acc[nf] = __builtin_amdgcn_mfma_f32_16x16x32_bf16(ah0, bh, acc[nf], 0, 0, 0);
      acc[nf] = __builtin_amdgcn_mfma_f32_16x16x32_bf16(ah0, bl, acc[nf], 0, 0, 0);
      acc[nf] = __builtin_amdgcn_mfma_f32_16x16x32_bf16(al0, bh, acc[nf], 0, 0, 0);
    }
  }
  // ---- epilogue ----
  float bgv[4];
  #pragma unroll
  for (int nf = 0; nf < 4; ++nf) bgv[nf] = bg[nfh*64 + nf*16 + l15];
  #pragma unroll
  for (int reg = 0; reg < 4; ++reg) {
    int row = r0 + w*16 + grp*4 + reg;
    #pragma unroll
    for (int nf = 0; nf < 4; ++nf) {
      int col = nf*16 + l15;
      float v = sigm(acc[nf][reg] + bgv[nf]);
      if (nfh == 0) {
        float ho = catP[(size_t)row*STR + col];
        zP[(size_t)row*STR + col] = v * ho;
      } else {
        Ug[(size_t)row*UU + col] = v;
      }
    }
  }
  if (nfh == 0 && l15 == 0) {
    #pragma unroll
    for (int reg = 0; reg < 4; ++reg) {
      int row = r0 + w*16 + grp*4 + reg;
      size_t zb = (size_t)row*STR;
      zP[zb + 64] = catP[zb + 64];
      zP[zb + 65] = (CATM == 1) ? catP[zb + 65] : 0.f;
      zP[zb + 66] = 0.f; zP[zb + 67] = 0.f;
    }
  }
}

// ================= cand GEMM (LDS-staged B, deep A-prefetch) =================
// 512 threads, 128 rows x 64 cols; grid = MR/128
template<bool DEC>
__global__ __launch_bounds__(512, 4) void k_cand(
    const float* __restrict__ zP, const float* __restrict__ T1P, const float* __restrict__ T2P,
    const unsigned short* __restrict__ Bpack, const float* __restrict__ bc,
    const float* __restrict__ Ug, const float* __restrict__ catCur,
    float* __restrict__ catNext,
    const float* __restrict__ Wp, const float* __restrict__ bp,
    float* __restrict__ out, const float* __restrict__ hist, int tpar) {
  __shared__ __align__(16) unsigned short Bl[PACK_HALF];
  int tid = threadIdx.x;
  int r0 = blockIdx.x * 128;
  int w = tid >> 6, lane = tid & 63, grp = lane >> 4, l15 = lane & 15;
  int row0 = r0 + w*16 + l15;

  float av[7][8];
  #pragma unroll
  for (int ks = 0; ks < 6; ++ks) {
    const float* p0 = (ks < 2) ? zP : ((ks < 4) ? T1P : T2P);
    const float* a0 = p0 + (size_t)row0*STR + (ks & 1)*32 + grp*8;
    *(float4*)(av[ks])     = *(const float4*)a0;
    *(float4*)(av[ks] + 4) = *(const float4*)(a0 + 4);
  }
  #pragma unroll
  for (int j2 = 0; j2 < 8; ++j2) av[6][j2] = 0.f;
  if (grp == 0) {
    size_t rb = (size_t)row0*STR + 64;
    if (!DEC) {
      av[6][0] = zP[rb];  av[6][1] = zP[rb + 1];
      av[6][2] = T1P[rb]; av[6][3] = T1P[rb + 1];
      av[6][4] = T2P[rb]; av[6][5] = T2P[rb + 1];
    } else {
      av[6][0] = zP[rb];
      av[6][1] = T1P[rb];
      av[6][2] = T2P[rb];
    }
  }

  {
    const float4* srcv = (const float4*)Bpack;
    float4* dstv = (float4*)Bl;
    #pragma unroll
    for (int i = 0; i < PACK_HALF/8/512; ++i) dstv[tid + 512*i] = srcv[tid + 512*i];
  }
  __syncthreads();

  ffrag acc[4];
  #pragma unroll
  for (int nf = 0; nf < 4; ++nf) acc[nf] = (ffrag){0.f, 0.f, 0.f, 0.f};
  #pragma unroll
  for (int ks = 0; ks < 7; ++ks) {
    bfrag ah0, al0;
    cvt8(av[ks], &ah0, &al0);
    #pragma unroll
    for (int nf = 0; nf < 4; ++nf) {
      const unsigned short* bb = Bl + (((size_t)(ks*4 + nf)*2)*64 + lane)*8;
      bfrag bh = *(const bfrag*)bb;
      bfrag bl = *(const bfrag*)(bb + 512);
      acc[nf] = __builtin_amdgcn_mfma_f32_16x16x32_bf16(ah0, bh, acc[nf], 0, 0, 0);
      acc[nf] = __builtin_amdgcn_mfma_f32_16x16x32_bf16(ah0, bl, acc[nf], 0, 0, 0);
      acc[nf] = __builtin_amdgcn_mfma_f32_16x16x32_bf16(al0, bh, acc[nf], 0, 0, 0);
    }
  }
  float bcv[4], wpv[4];
  #pragma unroll
  for (int nf = 0; nf < 4; ++nf) {
    bcv[nf] = bc[nf*16 + l15];
    wpv[nf] = DEC ? Wp[nf*16 + l15] : 0.f;
  }
  float bp0 = DEC ? bp[0] : 0.f;
  #pragma unroll
  for (int reg = 0; reg < 4; ++reg) {
    int row = r0 + w*16 + grp*4 + reg;
    float p = 0.f;
    #pragma unroll
    for (int nf = 0; nf < 4; ++nf) {
      int col = nf*16 + l15;
      float cf = tanhfast(acc[nf][reg] + bcv[nf]);
      float u  = Ug[(size_t)row*UU + col];
      float ho = catCur[(size_t)row*STR + col];
      float hv = u * ho + (1.0f - u) * cf;
      catNext[(size_t)row*STR + col] = hv;
      if (DEC) p = fmaf(hv, wpv[nf], p);
    }
    if (DEC) {
      p += __shfl_xor(p, 1, 64);
      p += __shfl_xor(p, 2, 64);
      p += __shfl_xor(p, 4, 64);
      p += __shfl_xor(p, 8, 64);
      if (l15 == 0) {
        float val = p + bp0;
        int n = row >> 5, b = row & 31;
        out[((size_t)b*HHH + tpar)*NN + n] = val;
        catNext[(size_t)row*STR + 64] = val;   // next decoder input
        catNext[(size_t)row*STR + 65] = 0.f;
      }
    } else {
      if (l15 == 0) {
        int n = row >> 5, b = row & 31;
        bool hv2 = tpar < LL;
        const float* hx = hist + (((size_t)(b*LL + tpar)) * NN + n) * 2;
        catNext[(size_t)row*STR + 64] = hv2 ? hx[0] : 0.f;
        catNext[(size_t)row*STR + 65] = hv2 ? hx[1] : 0.f;
      }
    }
  }
}

extern "C" void kernel_launch(void* const* d_in, const int* in_sizes, int n_in,
                              void* d_out, int out_size, void* d_ws, size_t ws_size,
                              hipStream_t stream) {
  (void)in_sizes; (void)n_in; (void)out_size; (void)ws_size;
  const float* hist = (const float*)d_in[0];
  const float* support = (const float*)d_in[1];
  const float* eWg = (const float*)d_in[2];
  const float* ebg = (const float*)d_in[3];
  const float* eWc = (const float*)d_in[4];
  const float* ebc = (const float*)d_in[5];
  const float* dWg = (const float*)d_in[6];
  const float* dbg = (const float*)d_in[7];
  const float* dWc = (const float*)d_in[8];
  const float* dbc = (const float*)d_in[9];
  const float* Wp  = (const float*)d_in[10];
  const float* bp  = (const float*)d_in[11];
  float* out = (float*)d_out;

  char* base = (char*)d_ws;
  size_t off = 0;
  auto carve = [&](size_t bytes) -> void* {
    void* p = base + off;
    off += (bytes + 255) & ~(size_t)255;
    return p;
  };
  int*   cnt   = (int*)carve(NN * 4);
  int*   rpB   = (int*)carve((NN + 1) * 4);
  int*   colsB = (int*)carve(CSR_CAP * 4);
  float* valsB = (float*)carve(CSR_CAP * 4);
  unsigned short* Pge = (unsigned short*)carve(2 * PACK_HALF * 2);
  unsigned short* Pgd = (unsigned short*)carve(2 * PACK_HALF * 2);
  unsigned short* Pce = (unsigned short*)carve((size_t)PACK_HALF * 2);
  unsigned short* Pcd = (unsigned short*)carve((size_t)PACK_HALF * 2);
  float* T1P  = (float*)carve((size_t)NN * SLAB * 4);
  float* T2P  = (float*)carve((size_t)NN * SLAB * 4);
  float* zP   = (float*)carve((size_t)NN * SLAB * 4);
  float* UgF  = (float*)carve((size_t)MR * UU * 4);
  float* catA = (float*)carve((size_t)NN * SLAB * 4);
  float* catB = (float*)carve((size_t)NN * SLAB * 4);

  hipMemsetAsync(catA, 0, (size_t)NN * SLAB * 4, stream);
  hipMemsetAsync(catB, 0, (size_t)NN * SLAB * 4, stream);

  k_row_count<<<NN, 256, 0, stream>>>(support, cnt);
  k_scan<<<1, 256, 0, stream>>>(cnt, rpB);
  k_fill<<<NN, 256, 0, stream>>>(support, rpB, colsB, valsB);
  k_pack<<<112, 256, 0, stream>>>(eWg, Pge, 2, 128);
  k_pack<<<56, 256, 0, stream>>>(eWc, Pce, 2, 64);
  k_pack<<<112, 256, 0, stream>>>(dWg, Pgd, 1, 128);
  k_pack<<<56, 256, 0, stream>>>(dWc, Pcd, 1, 64);
  k_setx<<<(MR*2 + 255)/256, 256, 0, stream>>>(hist, catA, 0);

  float* hc = catA; float* hn = catB;
  for (int t = 0; t < LL; ++t) {
    k_hop<<<NN*SEGS/2, 320, 0, stream>>>(rpB, colsB, valsB, hc, T1P);
    k_hop<<<NN*SEGS/2, 320, 0, stream>>>(rpB, colsB, valsB, T1P, T2P);
    k_gate<1><<<MR/128*2, 512, 0, stream>>>(hc, T1P, T2P, Pge, ebg, zP, UgF);
    k_hop<<<NN*SEGS/2, 320, 0, stream>>>(rpB, colsB, valsB, zP, T1P);
    k_hop<<<NN*SEGS/2, 320, 0, stream>>>(rpB, colsB, valsB, T1P, T2P);
    k_cand<false><<<MR/128, 512, 0, stream>>>(zP, T1P, T2P, Pce, ebc, UgF, hc, hn,
                                              Wp, bp, out, hist, t + 1);
    float* tmp = hc; hc = hn; hn = tmp;
  }
  for (int t = 0; t < HHH; ++t) {
    k_hop<<<NN*SEGS/2, 320, 0, stream>>>(rpB, colsB, valsB, hc, T1P);
    k_hop<<<NN*SEGS/2, 320, 0, stream>>>(rpB, colsB, valsB, T1P, T2P);
    k_gate<2><<<MR/128*2, 512, 0, stream>>>(hc, T1P, T2P, Pgd, dbg, zP, UgF);
    k_hop<<<NN*SEGS/2, 320, 0, stream>>>(rpB, colsB, valsB, zP, T1P);
    k_hop<<<NN*SEGS/2, 320, 0, stream>>>(rpB, colsB, valsB, T1P, T2P);
    k_cand<true><<<MR/128, 512, 0, stream>>>(zP, T1P, T2P, Pcd, dbc, UgF, hc, hn,
                                             Wp, bp, out, hist, t);
    float* tmp = hc; hc = hn; hn = tmp;
  }
}